// Round 3
// baseline (1055.461 us; speedup 1.0000x reference)
//
#include <hip/hip_runtime.h>

// Graph: N=100000 nodes (< 2^17), E=3.2M edges. Buckets of 128 nodes: col>>7.
#define BSHIFT 7
#define BWIDTH 128

// ---------------- kernels ----------------

__global__ void k_init(int* __restrict__ bcount, int* __restrict__ bfill,
                       float* __restrict__ gsum, int nbuck) {
    int i = blockIdx.x * blockDim.x + threadIdx.x;
    if (i < nbuck) { bcount[i] = 0; bfill[i] = 0; }
    if (i < 32) gsum[i] = 0.f;
}

// pass 1: per-bucket edge counts (LDS-aggregated histogram)
__global__ __launch_bounds__(256) void k_hist(const int* __restrict__ col,
        int* __restrict__ bcount, int E, int nbuck) {
    __shared__ int h[1024];
    for (int i = threadIdx.x; i < nbuck; i += 256) h[i] = 0;
    __syncthreads();
    int stride = gridDim.x * blockDim.x;
    for (int e = blockIdx.x * blockDim.x + threadIdx.x; e < E; e += stride)
        atomicAdd(&h[col[e] >> BSHIFT], 1);
    __syncthreads();
    for (int i = threadIdx.x; i < nbuck; i += 256) {
        int v = h[i];
        if (v) atomicAdd(&bcount[i], v);
    }
}

// exclusive scan of bucket counts (nbuck <= 1024), one block of 1024
__global__ void k_scanb(const int* __restrict__ bcount, int* __restrict__ bbase,
                        int* __restrict__ ptr, int nbuck, int E, int N) {
    __shared__ int s[1024];
    int t = threadIdx.x;
    int v = (t < nbuck) ? bcount[t] : 0;
    s[t] = v;
    __syncthreads();
    for (int off = 1; off < 1024; off <<= 1) {
        int u = (t >= off) ? s[t - off] : 0;
        __syncthreads();
        s[t] += u;
        __syncthreads();
    }
    if (t < nbuck) bbase[t] = s[t] - v;   // exclusive
    if (t == 0) ptr[N] = E;
}

// pass 2: scatter packed edges into bucket-grouped staging
__global__ __launch_bounds__(256) void k_scatter2(const int* __restrict__ row,
        const int* __restrict__ col, const int* __restrict__ bbase,
        int* __restrict__ bfill, unsigned* __restrict__ staging, int E) {
    int stride = gridDim.x * blockDim.x;
    for (int e = blockIdx.x * blockDim.x + threadIdx.x; e < E; e += stride) {
        int r = row[e];
        int c = col[e];
        int b = c >> BSHIFT;
        int pos = bbase[b] + atomicAdd(&bfill[b], 1);
        staging[pos] = (unsigned)r | ((unsigned)(c & (BWIDTH - 1)) << 17);
    }
}

// pass 3: per-bucket CSR build (local histogram + scan in LDS), writes ptr/dis/csr
__global__ __launch_bounds__(256) void k_build(const unsigned* __restrict__ staging,
        const int* __restrict__ bbase, const int* __restrict__ bcount,
        int* __restrict__ ptr, float* __restrict__ dis, int* __restrict__ csr, int N) {
    __shared__ int lhist[BWIDTH];
    __shared__ int lscan[BWIDTH];
    __shared__ int lfill[BWIDTH];
    int b = blockIdx.x;
    int base = bbase[b], cnt = bcount[b];
    int node0 = b << BSHIFT;
    int t = threadIdx.x;
    if (t < BWIDTH) { lhist[t] = 0; lfill[t] = 0; }
    __syncthreads();
    for (int i = t; i < cnt; i += 256)
        atomicAdd(&lhist[staging[base + i] >> 17], 1);
    __syncthreads();
    if (t < BWIDTH) lscan[t] = lhist[t];
    __syncthreads();
    for (int off = 1; off < BWIDTH; off <<= 1) {
        int u = 0;
        if (t < BWIDTH && t >= off) u = lscan[t - off];
        __syncthreads();
        if (t < BWIDTH) lscan[t] += u;
        __syncthreads();
    }
    if (t < BWIDTH) {
        int ex = lscan[t] - lhist[t];      // exclusive scan
        int node = node0 + t;
        if (node < N) {
            ptr[node] = base + ex;
            dis[node] = rsqrtf((float)(lhist[t] + 1));   // +1 self-loop
        }
        lscan[t] = ex;
    }
    __syncthreads();
    for (int i = t; i < cnt; i += 256) {
        unsigned p = staging[base + i];
        int c = p >> 17;
        int r = (int)(p & 0x1FFFFu);
        int pos = base + lscan[c] + atomicAdd(&lfill[c], 1);
        csr[pos] = r;
    }
}

// zs1[v] = x[v] * dis[v]
__global__ void k_zs1(const float4* __restrict__ x, const float* __restrict__ dis,
                      float4* __restrict__ zs1, int n) {
    int i = blockIdx.x * blockDim.x + threadIdx.x;
    if (i < n) {
        float d = dis[i];
        float4 v = x[i];
        v.x *= d; v.y *= d; v.z *= d; v.w *= d;
        zs1[i] = v;
    }
}

// fused: p1 = dis*(zs1 + gather) ; t = relu(p1@W1+b1) ; zs2 = (t@W2)*dis
__global__ __launch_bounds__(256) void k_prop1mlp(const float4* __restrict__ zs1,
        const int* __restrict__ csr, const int* __restrict__ ptr,
        const float* __restrict__ dis, const float* __restrict__ W1,
        const float* __restrict__ b1, const float* __restrict__ W2,
        float* __restrict__ zs2, int n) {
    __shared__ float sW1[256];
    __shared__ float sb1[64];
    __shared__ float sW2[2048];
    for (int i = threadIdx.x; i < 256; i += 256) sW1[i] = W1[i];
    if (threadIdx.x < 64) sb1[threadIdx.x] = b1[threadIdx.x];
    for (int i = threadIdx.x; i < 2048; i += 256) sW2[i] = W2[i];
    __syncthreads();
    int v = blockIdx.x * 256 + threadIdx.x;
    if (v >= n) return;
    int beg = ptr[v], end = ptr[v + 1];
    float4 a = zs1[v];
    for (int k = beg; k < end; k++) {
        float4 u = zs1[csr[k]];
        a.x += u.x; a.y += u.y; a.z += u.z; a.w += u.w;
    }
    float d = dis[v];
    a.x *= d; a.y *= d; a.z *= d; a.w *= d;
    float acc[32];
#pragma unroll
    for (int j = 0; j < 32; j++) acc[j] = 0.f;
    for (int k = 0; k < 64; k++) {
        float tv = fmaxf(a.x * sW1[k] + a.y * sW1[64 + k] + a.z * sW1[128 + k]
                         + a.w * sW1[192 + k] + sb1[k], 0.f);
#pragma unroll
        for (int j = 0; j < 32; j++) acc[j] += tv * sW2[k * 32 + j];
    }
#pragma unroll
    for (int j = 0; j < 32; j++) zs2[(size_t)v * 32 + j] = acc[j] * d;
}

// prop layer 2 (32 lanes per node) + relu(+b2) + global mean-pool partial sums
__global__ __launch_bounds__(256) void k_prop2(const float* __restrict__ zs2,
        const int* __restrict__ csr, const int* __restrict__ ptr,
        const float* __restrict__ dis, const float* __restrict__ b2,
        float* __restrict__ gsum, int n) {
    __shared__ float gacc[32];
    if (threadIdx.x < 32) gacc[threadIdx.x] = 0.f;
    __syncthreads();
    int f = threadIdx.x & 31;
    int v = (blockIdx.x * blockDim.x + threadIdx.x) >> 5;
    if (v < n) {
        int beg = ptr[v], end = ptr[v + 1];
        float a = zs2[(size_t)v * 32 + f];
        for (int k = beg; k < end; k++) {
            int u = csr[k];
            a += zs2[(size_t)u * 32 + f];
        }
        a = fmaxf(a * dis[v] + b2[f], 0.f);
        atomicAdd(&gacc[f], a);
    }
    __syncthreads();
    if (threadIdx.x < 32) atomicAdd(&gsum[threadIdx.x], gacc[threadIdx.x]);
}

// out = sigmoid( (gsum/n) @ Wfc + bfc )
__global__ void k_final(const float* __restrict__ gsum, const float* __restrict__ Wfc,
                        const float* __restrict__ bfc, float* __restrict__ out, int n) {
    __shared__ float s[32];
    int t = threadIdx.x;
    if (t < 32) s[t] = (gsum[t] / (float)n) * Wfc[t];
    __syncthreads();
    if (t == 0) {
        float a = 0.f;
        for (int i = 0; i < 32; i++) a += s[i];
        a += bfc[0];
        out[0] = 1.f / (1.f + expf(-a));
    }
}

// ---------------- launch ----------------

extern "C" void kernel_launch(void* const* d_in, const int* in_sizes, int n_in,
                              void* d_out, int out_size, void* d_ws, size_t ws_size,
                              hipStream_t stream) {
    const float* x    = (const float*)d_in[0];
    const int*   ei   = (const int*)d_in[1];     // int32 per harness contract
    const float* W1   = (const float*)d_in[2];
    const float* b1   = (const float*)d_in[3];
    const float* W2   = (const float*)d_in[4];
    const float* b2   = (const float*)d_in[5];
    const float* Wfc  = (const float*)d_in[6];
    const float* bfc  = (const float*)d_in[7];
    float* out = (float*)d_out;

    const int N = in_sizes[0] / 4;
    const int E = in_sizes[1] / 2;
    const int nbuck = (N + BWIDTH - 1) >> BSHIFT;   // 782 for N=100000 (<=1024)

    auto align = [](size_t v) { return (v + 255) & ~(size_t)255; };
    char* w = (char*)d_ws;
    int*   bcount = (int*)w;   w += align(1024 * 4);
    int*   bfill  = (int*)w;   w += align(1024 * 4);
    int*   bbase  = (int*)w;   w += align(1024 * 4);
    int*   ptr    = (int*)w;   w += align(((size_t)N + 1) * 4);
    float* dis    = (float*)w; w += align((size_t)N * 4);
    int*   csr    = (int*)w;   w += align((size_t)E * 4);
    // staging (E*4) aliases zs2 (N*32*4 >= E*4): staging dead before zs2 written
    char*  shared_slot = w;    w += align((size_t)N * 32 * 4);
    unsigned* staging = (unsigned*)shared_slot;
    float*    zs2     = (float*)shared_slot;
    float* zs1    = (float*)w; w += align((size_t)N * 16);
    float* gsum   = (float*)w; w += align(32 * 4);

    const int nb = (N + 255) / 256;

    k_init<<<4, 256, 0, stream>>>(bcount, bfill, gsum, nbuck);
    k_hist<<<512, 256, 0, stream>>>(ei + E, bcount, E, nbuck);
    k_scanb<<<1, 1024, 0, stream>>>(bcount, bbase, ptr, nbuck, E, N);
    k_scatter2<<<2048, 256, 0, stream>>>(ei, ei + E, bbase, bfill, staging, E);
    k_build<<<nbuck, 256, 0, stream>>>(staging, bbase, bcount, ptr, dis, csr, N);
    k_zs1<<<nb, 256, 0, stream>>>((const float4*)x, dis, (float4*)zs1, N);
    k_prop1mlp<<<nb, 256, 0, stream>>>((const float4*)zs1, csr, ptr, dis, W1, b1, W2, zs2, N);
    k_prop2<<<(N * 32 + 255) / 256, 256, 0, stream>>>(zs2, csr, ptr, dis, b2, gsum, N);
    k_final<<<1, 64, 0, stream>>>(gsum, Wfc, bfc, out, N);
}

// Round 4
// 551.705 us; speedup vs baseline: 1.9131x; 1.9131x over previous
//
#include <hip/hip_runtime.h>

#define NPASS 4

// ---------------- kernels ----------------

__global__ void k_init(int* __restrict__ deg, int* __restrict__ fill,
                       float* __restrict__ gsum, int n) {
    int i = blockIdx.x * blockDim.x + threadIdx.x;
    if (i < n) { deg[i] = 1; fill[i] = 0; }          // deg starts at 1 (self-loop)
    if (blockIdx.x == 0 && threadIdx.x < 32) gsum[threadIdx.x] = 0.f;
}

// histogram of in-degree over col = edge_index[1]
__global__ __launch_bounds__(256) void k_count(const int* __restrict__ col,
        int* __restrict__ deg, int E, int n) {
    int stride = gridDim.x * blockDim.x;
    for (int e = blockIdx.x * blockDim.x + threadIdx.x; e < E; e += stride) {
        int c = col[e];
        if ((unsigned)c < (unsigned)n) atomicAdd(&deg[c], 1);
    }
}

// dis = rsqrt(deg); per-block sum of (deg-1) for the scan
__global__ void k_dis_blocksum(const int* __restrict__ deg, float* __restrict__ dis,
                               int* __restrict__ partial, int n) {
    __shared__ int s[256];
    int i = blockIdx.x * 256 + threadIdx.x;
    int c = 0;
    if (i < n) { int d = deg[i]; dis[i] = rsqrtf((float)d); c = d - 1; }
    s[threadIdx.x] = c;
    __syncthreads();
    for (int st = 128; st > 0; st >>= 1) {
        if (threadIdx.x < st) s[threadIdx.x] += s[threadIdx.x + st];
        __syncthreads();
    }
    if (threadIdx.x == 0) partial[blockIdx.x] = s[0];
}

// exclusive scan of block partials (nb <= 512); also writes ptr[N] = E
__global__ void k_scan_partials(int* __restrict__ partial, int nb,
                                int* __restrict__ ptr, int N, int E) {
    __shared__ int s[512];
    int t = threadIdx.x;
    int val = (t < nb) ? partial[t] : 0;
    s[t] = val;
    __syncthreads();
    for (int off = 1; off < 512; off <<= 1) {
        int v = (t >= off) ? s[t - off] : 0;
        __syncthreads();
        s[t] += v;
        __syncthreads();
    }
    if (t < nb) partial[t] = s[t] - val;   // exclusive
    if (t == 0) ptr[N] = E;
}

// ptr[v] = block-exclusive-scan(deg-1) + partial[block]
__global__ void k_ptr(const int* __restrict__ deg, const int* __restrict__ partial,
                      int* __restrict__ ptr, int n) {
    __shared__ int s[256];
    int i = blockIdx.x * 256 + threadIdx.x;
    int c = (i < n) ? (deg[i] - 1) : 0;
    int val = c;
    s[threadIdx.x] = c;
    __syncthreads();
    for (int off = 1; off < 256; off <<= 1) {
        int v = (threadIdx.x >= off) ? s[threadIdx.x - off] : 0;
        __syncthreads();
        s[threadIdx.x] += v;
        __syncthreads();
    }
    if (i < n) ptr[i] = s[threadIdx.x] - val + partial[blockIdx.x];
}

// windowed scatter: only place edges whose col is in [lo, hi).
// Both row & col are read coalesced every pass (asm pin stops load sinking);
// the CSR write window per pass is ~E/NPASS*4B -> stays L2-resident.
__global__ __launch_bounds__(256) void k_scatter_win(const int* __restrict__ row,
        const int* __restrict__ col, const int* __restrict__ ptr,
        int* __restrict__ fill, int* __restrict__ csr, int E, int lo, int hi) {
    int stride = gridDim.x * blockDim.x;
    for (int e = blockIdx.x * blockDim.x + threadIdx.x; e < E; e += stride) {
        int c = col[e];
        int r = row[e];
        asm volatile("" :: "v"(r));          // keep row load coalesced & unconditional
        if (c >= lo && c < hi) {
            int pos = ptr[c] + atomicAdd(&fill[c], 1);
            csr[pos] = r;
        }
    }
}

// zs1[v] = x[v] * dis[v]
__global__ void k_zs1(const float4* __restrict__ x, const float* __restrict__ dis,
                      float4* __restrict__ zs1, int n) {
    int i = blockIdx.x * blockDim.x + threadIdx.x;
    if (i < n) {
        float d = dis[i];
        float4 v = x[i];
        v.x *= d; v.y *= d; v.z *= d; v.w *= d;
        zs1[i] = v;
    }
}

// fused: p1 = dis*(zs1 + gather) ; t = relu(p1@W1+b1) ; zs2 = (t@W2)*dis
__global__ __launch_bounds__(256) void k_prop1mlp(const float4* __restrict__ zs1,
        const int* __restrict__ csr, const int* __restrict__ ptr,
        const float* __restrict__ dis, const float* __restrict__ W1,
        const float* __restrict__ b1, const float* __restrict__ W2,
        float* __restrict__ zs2, int n) {
    __shared__ float sW1[256];
    __shared__ float sb1[64];
    __shared__ float sW2[2048];
    for (int i = threadIdx.x; i < 256; i += 256) sW1[i] = W1[i];
    if (threadIdx.x < 64) sb1[threadIdx.x] = b1[threadIdx.x];
    for (int i = threadIdx.x; i < 2048; i += 256) sW2[i] = W2[i];
    __syncthreads();
    int v = blockIdx.x * 256 + threadIdx.x;
    if (v >= n) return;
    int beg = ptr[v], end = ptr[v + 1];
    float4 a = zs1[v];
    for (int k = beg; k < end; k++) {
        float4 u = zs1[csr[k]];
        a.x += u.x; a.y += u.y; a.z += u.z; a.w += u.w;
    }
    float d = dis[v];
    a.x *= d; a.y *= d; a.z *= d; a.w *= d;
    float acc[32];
#pragma unroll
    for (int j = 0; j < 32; j++) acc[j] = 0.f;
    for (int k = 0; k < 64; k++) {
        float tv = fmaxf(a.x * sW1[k] + a.y * sW1[64 + k] + a.z * sW1[128 + k]
                         + a.w * sW1[192 + k] + sb1[k], 0.f);
#pragma unroll
        for (int j = 0; j < 32; j++) acc[j] += tv * sW2[k * 32 + j];
    }
#pragma unroll
    for (int j = 0; j < 32; j++) zs2[(size_t)v * 32 + j] = acc[j] * d;
}

// prop layer 2 (32 lanes per node, gather unrolled x4) + relu(+b2) + mean-pool partials
__global__ __launch_bounds__(256) void k_prop2(const float* __restrict__ zs2,
        const int* __restrict__ csr, const int* __restrict__ ptr,
        const float* __restrict__ dis, const float* __restrict__ b2,
        float* __restrict__ gsum, int n) {
    __shared__ float gacc[32];
    if (threadIdx.x < 32) gacc[threadIdx.x] = 0.f;
    __syncthreads();
    int f = threadIdx.x & 31;
    int v = (blockIdx.x * blockDim.x + threadIdx.x) >> 5;
    if (v < n) {
        int beg = ptr[v], end = ptr[v + 1];
        float a = zs2[(size_t)v * 32 + f];
        int k = beg;
        for (; k + 3 < end; k += 4) {
            int u0 = csr[k], u1 = csr[k + 1], u2 = csr[k + 2], u3 = csr[k + 3];
            float t0 = zs2[(size_t)u0 * 32 + f];
            float t1 = zs2[(size_t)u1 * 32 + f];
            float t2 = zs2[(size_t)u2 * 32 + f];
            float t3 = zs2[(size_t)u3 * 32 + f];
            a += (t0 + t1) + (t2 + t3);
        }
        for (; k < end; k++) a += zs2[(size_t)csr[k] * 32 + f];
        a = fmaxf(a * dis[v] + b2[f], 0.f);
        atomicAdd(&gacc[f], a);
    }
    __syncthreads();
    if (threadIdx.x < 32) atomicAdd(&gsum[threadIdx.x], gacc[threadIdx.x]);
}

// out = sigmoid( (gsum/n) @ Wfc + bfc )
__global__ void k_final(const float* __restrict__ gsum, const float* __restrict__ Wfc,
                        const float* __restrict__ bfc, float* __restrict__ out, int n) {
    __shared__ float s[32];
    int t = threadIdx.x;
    if (t < 32) s[t] = (gsum[t] / (float)n) * Wfc[t];
    __syncthreads();
    if (t == 0) {
        float a = 0.f;
        for (int i = 0; i < 32; i++) a += s[i];
        a += bfc[0];
        out[0] = 1.f / (1.f + expf(-a));
    }
}

// ---------------- launch ----------------

extern "C" void kernel_launch(void* const* d_in, const int* in_sizes, int n_in,
                              void* d_out, int out_size, void* d_ws, size_t ws_size,
                              hipStream_t stream) {
    const float* x    = (const float*)d_in[0];
    const int*   ei   = (const int*)d_in[1];     // int32 per harness contract
    const float* W1   = (const float*)d_in[2];
    const float* b1   = (const float*)d_in[3];
    const float* W2   = (const float*)d_in[4];
    const float* b2   = (const float*)d_in[5];
    const float* Wfc  = (const float*)d_in[6];
    const float* bfc  = (const float*)d_in[7];
    float* out = (float*)d_out;

    const int N = in_sizes[0] / 4;
    const int E = in_sizes[1] / 2;

    auto align = [](size_t v) { return (v + 255) & ~(size_t)255; };
    char* w = (char*)d_ws;
    int*   deg     = (int*)w;    w += align((size_t)N * 4);
    int*   fill    = (int*)w;    w += align((size_t)N * 4);
    float* dis     = (float*)w;  w += align((size_t)N * 4);
    int*   ptr     = (int*)w;    w += align(((size_t)N + 1) * 4);
    int*   partial = (int*)w;    w += align(512 * 4);
    int*   csr     = (int*)w;    w += align((size_t)E * 4);
    float* zs1     = (float*)w;  w += align((size_t)N * 16);
    float* zs2     = (float*)w;  w += align((size_t)N * 32 * 4);
    float* gsum    = (float*)w;  w += align(32 * 4);

    const int nb = (N + 255) / 256;   // 391 for N=100000 (<=512)

    k_init<<<nb, 256, 0, stream>>>(deg, fill, gsum, N);
    k_count<<<2048, 256, 0, stream>>>(ei + E, deg, E, N);
    k_dis_blocksum<<<nb, 256, 0, stream>>>(deg, dis, partial, N);
    k_scan_partials<<<1, 512, 0, stream>>>(partial, nb, ptr, N, E);
    k_ptr<<<nb, 256, 0, stream>>>(deg, partial, ptr, N);
    const int wnd = (N + NPASS - 1) / NPASS;
    for (int p = 0; p < NPASS; p++) {
        int lo = p * wnd;
        int hi = (lo + wnd < N) ? lo + wnd : N;
        k_scatter_win<<<2048, 256, 0, stream>>>(ei, ei + E, ptr, fill, csr, E, lo, hi);
    }
    k_zs1<<<nb, 256, 0, stream>>>((const float4*)x, dis, (float4*)zs1, N);
    k_prop1mlp<<<nb, 256, 0, stream>>>((const float4*)zs1, csr, ptr, dis, W1, b1, W2, zs2, N);
    k_prop2<<<(N * 32 + 255) / 256, 256, 0, stream>>>(zs2, csr, ptr, dis, b2, gsum, N);
    k_final<<<1, 64, 0, stream>>>(gsum, Wfc, bfc, out, N);
}

// Round 5
// 476.054 us; speedup vs baseline: 2.2171x; 1.1589x over previous
//
#include <hip/hip_runtime.h>

#define NPASS 4
typedef int v4i __attribute__((ext_vector_type(4)));

// ---------------- kernels ----------------

__global__ void k_init(int* __restrict__ deg, int* __restrict__ fillLo,
                       int* __restrict__ fillHi, float* __restrict__ gsum, int n) {
    int i = blockIdx.x * blockDim.x + threadIdx.x;
    if (i < n) { deg[i] = 1; fillLo[i] = 0; fillHi[i] = 0; }   // deg=1: self-loop
    if (blockIdx.x == 0 && threadIdx.x < 32) gsum[threadIdx.x] = 0.f;
}

// in-degree histogram over col (int4 nontemporal loads, fire-and-forget atomics)
__global__ __launch_bounds__(256) void k_count(const v4i* __restrict__ col4,
        int* __restrict__ deg, int E4) {
    int stride = gridDim.x * blockDim.x;
    for (int i = blockIdx.x * blockDim.x + threadIdx.x; i < E4; i += stride) {
        v4i c = __builtin_nontemporal_load(&col4[i]);
        atomicAdd(&deg[c[0]], 1);
        atomicAdd(&deg[c[1]], 1);
        atomicAdd(&deg[c[2]], 1);
        atomicAdd(&deg[c[3]], 1);
    }
}

// dis = rsqrt(deg); per-block sum of (deg-1)
__global__ void k_dis_blocksum(const int* __restrict__ deg, float* __restrict__ dis,
                               int* __restrict__ partial, int n) {
    __shared__ int s[256];
    int i = blockIdx.x * 256 + threadIdx.x;
    int c = 0;
    if (i < n) { int d = deg[i]; dis[i] = rsqrtf((float)d); c = d - 1; }
    s[threadIdx.x] = c;
    __syncthreads();
    for (int st = 128; st > 0; st >>= 1) {
        if (threadIdx.x < st) s[threadIdx.x] += s[threadIdx.x + st];
        __syncthreads();
    }
    if (threadIdx.x == 0) partial[blockIdx.x] = s[0];
}

// exclusive scan of block partials (nb <= 512); also ptr[N] = E
__global__ void k_scan_partials(int* __restrict__ partial, int nb,
                                int* __restrict__ ptr, int N, int E) {
    __shared__ int s[512];
    int t = threadIdx.x;
    int val = (t < nb) ? partial[t] : 0;
    s[t] = val;
    __syncthreads();
    for (int off = 1; off < 512; off <<= 1) {
        int v = (t >= off) ? s[t - off] : 0;
        __syncthreads();
        s[t] += v;
        __syncthreads();
    }
    if (t < nb) partial[t] = s[t] - val;
    if (t == 0) ptr[N] = E;
}

// ptr[v] = block-exclusive-scan(deg-1) + partial[block]
__global__ void k_ptr(const int* __restrict__ deg, const int* __restrict__ partial,
                      int* __restrict__ ptr, int n) {
    __shared__ int s[256];
    int i = blockIdx.x * 256 + threadIdx.x;
    int c = (i < n) ? (deg[i] - 1) : 0;
    int val = c;
    s[threadIdx.x] = c;
    __syncthreads();
    for (int off = 1; off < 256; off <<= 1) {
        int v = (threadIdx.x >= off) ? s[threadIdx.x - off] : 0;
        __syncthreads();
        s[threadIdx.x] += v;
        __syncthreads();
    }
    if (i < n) ptr[i] = s[threadIdx.x] - val + partial[blockIdx.x];
}

// windowed scatter with source-split placement:
//   sources < mid fill from the front, sources >= mid fill from the back.
// 4 edges per thread -> 4 independent atomic->store chains (ILP).
__global__ __launch_bounds__(256) void k_scatter_win(const v4i* __restrict__ row4,
        const v4i* __restrict__ col4, const int* __restrict__ ptr,
        int* __restrict__ fillLo, int* __restrict__ fillHi, int* __restrict__ csr,
        int E4, int lo, int hi, int mid) {
    int stride = gridDim.x * blockDim.x;
    for (int i = blockIdx.x * blockDim.x + threadIdx.x; i < E4; i += stride) {
        v4i c = __builtin_nontemporal_load(&col4[i]);
        v4i r = __builtin_nontemporal_load(&row4[i]);
#pragma unroll
        for (int q = 0; q < 4; q++) {
            int cc = c[q], rr = r[q];
            if (cc >= lo && cc < hi) {
                int pos;
                if (rr < mid) pos = ptr[cc] + atomicAdd(&fillLo[cc], 1);
                else          pos = ptr[cc + 1] - 1 - atomicAdd(&fillHi[cc], 1);
                csr[pos] = rr;
            }
        }
    }
}

// zs1[v] = x[v] * dis[v]
__global__ void k_zs1(const float4* __restrict__ x, const float* __restrict__ dis,
                      float4* __restrict__ zs1, int n) {
    int i = blockIdx.x * blockDim.x + threadIdx.x;
    if (i < n) {
        float d = dis[i];
        float4 v = x[i];
        v.x *= d; v.y *= d; v.z *= d; v.w *= d;
        zs1[i] = v;
    }
}

__device__ __forceinline__ unsigned f2bf(float f) {   // RNE f32 -> bf16
    unsigned u = __float_as_uint(f);
    return (u + 0x7fffu + ((u >> 16) & 1u)) >> 16;
}

// fused: p1 = dis*(zs1+gather); t = relu(p1@W1+b1); zs2h = pack_bf16((t@W2)*dis)
__global__ __launch_bounds__(256) void k_prop1mlp(const float4* __restrict__ zs1,
        const int* __restrict__ csr, const int* __restrict__ ptr,
        const float* __restrict__ dis, const float* __restrict__ W1,
        const float* __restrict__ b1, const float* __restrict__ W2,
        uint4* __restrict__ zs2h, int n) {
    __shared__ float sW1[256];
    __shared__ float sb1[64];
    __shared__ float sW2[2048];
    for (int i = threadIdx.x; i < 256; i += 256) sW1[i] = W1[i];
    if (threadIdx.x < 64) sb1[threadIdx.x] = b1[threadIdx.x];
    for (int i = threadIdx.x; i < 2048; i += 256) sW2[i] = W2[i];
    __syncthreads();
    int v = blockIdx.x * 256 + threadIdx.x;
    if (v >= n) return;
    int beg = ptr[v], end = ptr[v + 1];
    float4 a = zs1[v];
    int k = beg;
    for (; k + 3 < end; k += 4) {
        int s0 = csr[k], s1 = csr[k + 1], s2 = csr[k + 2], s3 = csr[k + 3];
        float4 u0 = zs1[s0], u1 = zs1[s1], u2 = zs1[s2], u3 = zs1[s3];
        a.x += (u0.x + u1.x) + (u2.x + u3.x);
        a.y += (u0.y + u1.y) + (u2.y + u3.y);
        a.z += (u0.z + u1.z) + (u2.z + u3.z);
        a.w += (u0.w + u1.w) + (u2.w + u3.w);
    }
    for (; k < end; k++) {
        float4 u = zs1[csr[k]];
        a.x += u.x; a.y += u.y; a.z += u.z; a.w += u.w;
    }
    float d = dis[v];
    a.x *= d; a.y *= d; a.z *= d; a.w *= d;
    float acc[32];
#pragma unroll
    for (int j = 0; j < 32; j++) acc[j] = 0.f;
    for (int kk = 0; kk < 64; kk++) {
        float tv = fmaxf(a.x * sW1[kk] + a.y * sW1[64 + kk] + a.z * sW1[128 + kk]
                         + a.w * sW1[192 + kk] + sb1[kk], 0.f);
#pragma unroll
        for (int j = 0; j < 32; j++) acc[j] += tv * sW2[kk * 32 + j];
    }
    uint4 pk[4];
#pragma unroll
    for (int q = 0; q < 4; q++) {
        pk[q].x = f2bf(acc[8 * q + 0] * d) | (f2bf(acc[8 * q + 1] * d) << 16);
        pk[q].y = f2bf(acc[8 * q + 2] * d) | (f2bf(acc[8 * q + 3] * d) << 16);
        pk[q].z = f2bf(acc[8 * q + 4] * d) | (f2bf(acc[8 * q + 5] * d) << 16);
        pk[q].w = f2bf(acc[8 * q + 6] * d) | (f2bf(acc[8 * q + 7] * d) << 16);
    }
#pragma unroll
    for (int q = 0; q < 4; q++) zs2h[(size_t)v * 4 + q] = pk[q];
}

// prop layer 2: 16 lanes/node, bf16x2 per lane (64B line per gather),
// two source-window phases (each 3.2MB footprint, L2-resident), x4 unroll.
__global__ __launch_bounds__(256) void k_prop2(const unsigned* __restrict__ zs2h,
        const int* __restrict__ csr, const int* __restrict__ ptr,
        const int* __restrict__ cntLo, const float* __restrict__ dis,
        const float* __restrict__ b2, float* __restrict__ gsum, int n) {
    __shared__ float gacc[32];
    if (threadIdx.x < 32) gacc[threadIdx.x] = 0.f;
    __syncthreads();
    int j = threadIdx.x & 15;
    int v = blockIdx.x * 16 + (threadIdx.x >> 4);
    if (v < n) {
        int beg = ptr[v], end = ptr[v + 1];
        int mid = beg + cntLo[v];
        unsigned su = zs2h[(size_t)v * 16 + j];
        float a0 = __uint_as_float(su << 16);
        float a1 = __uint_as_float(su & 0xffff0000u);
        int k = beg;
#pragma unroll 1
        for (int phase = 0; phase < 2; phase++) {
            int stop = phase ? end : mid;
            for (; k + 3 < stop; k += 4) {
                int s0 = csr[k], s1 = csr[k + 1], s2 = csr[k + 2], s3 = csr[k + 3];
                unsigned u0 = zs2h[(size_t)s0 * 16 + j];
                unsigned u1 = zs2h[(size_t)s1 * 16 + j];
                unsigned u2 = zs2h[(size_t)s2 * 16 + j];
                unsigned u3 = zs2h[(size_t)s3 * 16 + j];
                a0 += (__uint_as_float(u0 << 16) + __uint_as_float(u1 << 16))
                    + (__uint_as_float(u2 << 16) + __uint_as_float(u3 << 16));
                a1 += (__uint_as_float(u0 & 0xffff0000u) + __uint_as_float(u1 & 0xffff0000u))
                    + (__uint_as_float(u2 & 0xffff0000u) + __uint_as_float(u3 & 0xffff0000u));
            }
            for (; k < stop; k++) {
                unsigned u = zs2h[(size_t)csr[k] * 16 + j];
                a0 += __uint_as_float(u << 16);
                a1 += __uint_as_float(u & 0xffff0000u);
            }
        }
        float d = dis[v];
        a0 = fmaxf(a0 * d + b2[2 * j], 0.f);
        a1 = fmaxf(a1 * d + b2[2 * j + 1], 0.f);
        atomicAdd(&gacc[2 * j], a0);
        atomicAdd(&gacc[2 * j + 1], a1);
    }
    __syncthreads();
    if (threadIdx.x < 32) atomicAdd(&gsum[threadIdx.x], gacc[threadIdx.x]);
}

// out = sigmoid( (gsum/n) @ Wfc + bfc )
__global__ void k_final(const float* __restrict__ gsum, const float* __restrict__ Wfc,
                        const float* __restrict__ bfc, float* __restrict__ out, int n) {
    __shared__ float s[32];
    int t = threadIdx.x;
    if (t < 32) s[t] = (gsum[t] / (float)n) * Wfc[t];
    __syncthreads();
    if (t == 0) {
        float a = 0.f;
        for (int i = 0; i < 32; i++) a += s[i];
        a += bfc[0];
        out[0] = 1.f / (1.f + expf(-a));
    }
}

// ---------------- launch ----------------

extern "C" void kernel_launch(void* const* d_in, const int* in_sizes, int n_in,
                              void* d_out, int out_size, void* d_ws, size_t ws_size,
                              hipStream_t stream) {
    const float* x    = (const float*)d_in[0];
    const int*   ei   = (const int*)d_in[1];     // int32 per harness contract
    const float* W1   = (const float*)d_in[2];
    const float* b1   = (const float*)d_in[3];
    const float* W2   = (const float*)d_in[4];
    const float* b2   = (const float*)d_in[5];
    const float* Wfc  = (const float*)d_in[6];
    const float* bfc  = (const float*)d_in[7];
    float* out = (float*)d_out;

    const int N = in_sizes[0] / 4;
    const int E = in_sizes[1] / 2;
    const int E4 = E / 4;                 // E = 3.2M, divisible by 4
    const int mid = N / 2;

    auto align = [](size_t v) { return (v + 255) & ~(size_t)255; };
    char* w = (char*)d_ws;
    int*      deg     = (int*)w;      w += align((size_t)N * 4);
    int*      fillLo  = (int*)w;      w += align((size_t)N * 4);
    int*      fillHi  = (int*)w;      w += align((size_t)N * 4);
    float*    dis     = (float*)w;    w += align((size_t)N * 4);
    int*      ptr     = (int*)w;      w += align(((size_t)N + 1) * 4);
    int*      partial = (int*)w;      w += align(512 * 4);
    int*      csr     = (int*)w;      w += align((size_t)E * 4);
    float*    zs1     = (float*)w;    w += align((size_t)N * 16);
    unsigned* zs2h    = (unsigned*)w; w += align((size_t)N * 64);
    float*    gsum    = (float*)w;    w += align(32 * 4);

    const int nb = (N + 255) / 256;

    k_init<<<nb, 256, 0, stream>>>(deg, fillLo, fillHi, gsum, N);
    k_count<<<2048, 256, 0, stream>>>((const v4i*)(ei + E), deg, E4);
    k_dis_blocksum<<<nb, 256, 0, stream>>>(deg, dis, partial, N);
    k_scan_partials<<<1, 512, 0, stream>>>(partial, nb, ptr, N, E);
    k_ptr<<<nb, 256, 0, stream>>>(deg, partial, ptr, N);
    const int wnd = (N + NPASS - 1) / NPASS;
    for (int p = 0; p < NPASS; p++) {
        int lo = p * wnd;
        int hi = (lo + wnd < N) ? lo + wnd : N;
        k_scatter_win<<<2048, 256, 0, stream>>>((const v4i*)ei, (const v4i*)(ei + E),
                                                ptr, fillLo, fillHi, csr, E4, lo, hi, mid);
    }
    k_zs1<<<nb, 256, 0, stream>>>((const float4*)x, dis, (float4*)zs1, N);
    k_prop1mlp<<<nb, 256, 0, stream>>>((const float4*)zs1, csr, ptr, dis, W1, b1, W2,
                                       (uint4*)zs2h, N);
    k_prop2<<<(N + 15) / 16, 256, 0, stream>>>(zs2h, csr, ptr, fillLo, dis, b2, gsum, N);
    k_final<<<1, 64, 0, stream>>>(gsum, Wfc, bfc, out, N);
}

// Round 6
// 247.392 us; speedup vs baseline: 4.2664x; 1.9243x over previous
//
#include <hip/hip_runtime.h>

#define BSHIFT 7
#define BWIDTH 128
#define PBLK   256        // chunks for hist/place (also their grid size)
#define PTHR   1024

typedef int v4i __attribute__((ext_vector_type(4)));

// ---------------- CSR build (global-atomic-free) ----------------

// per-chunk bucket histogram -> hh[b*PBLK + chunk]
__global__ __launch_bounds__(PTHR) void k_histb(const v4i* __restrict__ col4,
        int E4, int nbuck, int* __restrict__ hh) {
    __shared__ int h[1024];
    int t = threadIdx.x;
    for (int i = t; i < nbuck; i += PTHR) h[i] = 0;
    __syncthreads();
    int per = (E4 + PBLK - 1) / PBLK;
    int beg = blockIdx.x * per;
    int end = min(beg + per, E4);
    for (int i = beg + t; i < end; i += PTHR) {
        v4i c = __builtin_nontemporal_load(&col4[i]);
        atomicAdd(&h[c[0] >> BSHIFT], 1);
        atomicAdd(&h[c[1] >> BSHIFT], 1);
        atomicAdd(&h[c[2] >> BSHIFT], 1);
        atomicAdd(&h[c[3] >> BSHIFT], 1);
    }
    __syncthreads();
    for (int b = t; b < nbuck; b += PTHR)
        hh[b * PBLK + blockIdx.x] = h[b];
}

// exclusive scan of hh, 1024-chunks; part[k] = chunk total
__global__ __launch_bounds__(1024) void k_scanA(int* __restrict__ hh, int total,
                                                int* __restrict__ part) {
    __shared__ int s[1024];
    int t = threadIdx.x;
    int i = blockIdx.x * 1024 + t;
    int v = (i < total) ? hh[i] : 0;
    s[t] = v;
    __syncthreads();
    for (int off = 1; off < 1024; off <<= 1) {
        int u = (t >= off) ? s[t - off] : 0;
        __syncthreads();
        s[t] += u;
        __syncthreads();
    }
    if (i < total) hh[i] = s[t] - v;            // exclusive within chunk
    if (t == 1023) part[blockIdx.x] = s[t];     // chunk total
}

// exclusive scan of chunk totals (+ gsum zero, ptr[N]=E)
__global__ __launch_bounds__(1024) void k_scanB(int* __restrict__ part, int nch,
        float* __restrict__ gsum, int* __restrict__ ptr, int N, int E) {
    __shared__ int s[1024];
    int t = threadIdx.x;
    int v = (t < nch) ? part[t] : 0;
    s[t] = v;
    __syncthreads();
    for (int off = 1; off < 1024; off <<= 1) {
        int u = (t >= off) ? s[t - off] : 0;
        __syncthreads();
        s[t] += u;
        __syncthreads();
    }
    if (t < nch) part[t] = s[t] - v;
    if (t < 32) gsum[t] = 0.f;
    if (t == 0) ptr[N] = E;
}

// add chunk offsets back
__global__ __launch_bounds__(1024) void k_scanC(int* __restrict__ hh, int total,
                                                const int* __restrict__ part) {
    int i = blockIdx.x * 1024 + threadIdx.x;
    if (i < total) hh[i] += part[blockIdx.x];
}

// place packed edges into bucket-grouped staging; bases precomputed, LDS rank only
__global__ __launch_bounds__(PTHR) void k_place(const v4i* __restrict__ row4,
        const v4i* __restrict__ col4, const int* __restrict__ hh,
        unsigned* __restrict__ staging, int E4, int nbuck) {
    __shared__ int sbase[1024];
    __shared__ int lfill[1024];
    int t = threadIdx.x;
    for (int b = t; b < nbuck; b += PTHR) {
        sbase[b] = hh[b * PBLK + blockIdx.x];
        lfill[b] = 0;
    }
    __syncthreads();
    int per = (E4 + PBLK - 1) / PBLK;
    int beg = blockIdx.x * per;
    int end = min(beg + per, E4);
    for (int i = beg + t; i < end; i += PTHR) {
        v4i c = __builtin_nontemporal_load(&col4[i]);
        v4i r = __builtin_nontemporal_load(&row4[i]);
#pragma unroll
        for (int q = 0; q < 4; q++) {
            int b = c[q] >> BSHIFT;
            int pos = sbase[b] + atomicAdd(&lfill[b], 1);
            staging[pos] = (unsigned)r[q] | ((unsigned)(c[q] & (BWIDTH - 1)) << 17);
        }
    }
}

// per-bucket: node degrees, ptr/dis/cntLo, CSR with lo|hi source split
__global__ __launch_bounds__(256) void k_build(const unsigned* __restrict__ staging,
        const int* __restrict__ hh, int* __restrict__ ptr, int* __restrict__ cntLo,
        float* __restrict__ dis, int* __restrict__ csr, int N, int E, int nbuck, int mid) {
    __shared__ int hist[BWIDTH], histLo[BWIDTH], scn[BWIDTH], fLo[BWIDTH], fHi[BWIDTH];
    int b = blockIdx.x;
    int base = hh[b * PBLK];
    int nxt  = (b + 1 < nbuck) ? hh[(b + 1) * PBLK] : E;
    int cnt = nxt - base;
    int t = threadIdx.x;
    if (t < BWIDTH) { hist[t] = 0; histLo[t] = 0; fLo[t] = 0; fHi[t] = 0; }
    __syncthreads();
    for (int i = t; i < cnt; i += 256) {
        unsigned p = staging[base + i];
        int c = p >> 17;
        atomicAdd(&hist[c], 1);
        if ((int)(p & 0x1FFFFu) < mid) atomicAdd(&histLo[c], 1);
    }
    __syncthreads();
    if (t < BWIDTH) scn[t] = hist[t];
    __syncthreads();
    for (int off = 1; off < BWIDTH; off <<= 1) {
        int u = (t < BWIDTH && t >= off) ? scn[t - off] : 0;
        __syncthreads();
        if (t < BWIDTH) scn[t] += u;
        __syncthreads();
    }
    if (t < BWIDTH) {
        int ex = scn[t] - hist[t];
        scn[t] = ex;
        int node = (b << BSHIFT) + t;
        if (node < N) {
            ptr[node]   = base + ex;
            cntLo[node] = histLo[t];
            dis[node]   = rsqrtf((float)(hist[t] + 1));   // +1 self-loop
        }
    }
    __syncthreads();
    for (int i = t; i < cnt; i += 256) {
        unsigned p = staging[base + i];
        int c = p >> 17;
        int r = (int)(p & 0x1FFFFu);
        int pos;
        if (r < mid) pos = base + scn[c] + atomicAdd(&fLo[c], 1);
        else         pos = base + scn[c] + histLo[c] + atomicAdd(&fHi[c], 1);
        csr[pos] = r;
    }
}

// ---------------- GNN compute ----------------

__global__ void k_zs1(const float4* __restrict__ x, const float* __restrict__ dis,
                      float4* __restrict__ zs1, int n) {
    int i = blockIdx.x * blockDim.x + threadIdx.x;
    if (i < n) {
        float d = dis[i];
        float4 v = x[i];
        v.x *= d; v.y *= d; v.z *= d; v.w *= d;
        zs1[i] = v;
    }
}

__device__ __forceinline__ unsigned f2bf(float f) {   // RNE f32 -> bf16
    unsigned u = __float_as_uint(f);
    return (u + 0x7fffu + ((u >> 16) & 1u)) >> 16;
}

// fused: p1 = dis*(zs1+gather); t = relu(p1@W1+b1); zs2h = pack_bf16((t@W2)*dis)
__global__ __launch_bounds__(256) void k_prop1mlp(const float4* __restrict__ zs1,
        const int* __restrict__ csr, const int* __restrict__ ptr,
        const float* __restrict__ dis, const float* __restrict__ W1,
        const float* __restrict__ b1, const float* __restrict__ W2,
        uint4* __restrict__ zs2h, int n) {
    __shared__ float sW1[256];
    __shared__ float sb1[64];
    __shared__ float sW2[2048];
    for (int i = threadIdx.x; i < 256; i += 256) sW1[i] = W1[i];
    if (threadIdx.x < 64) sb1[threadIdx.x] = b1[threadIdx.x];
    for (int i = threadIdx.x; i < 2048; i += 256) sW2[i] = W2[i];
    __syncthreads();
    int v = blockIdx.x * 256 + threadIdx.x;
    if (v >= n) return;
    int beg = ptr[v], end = ptr[v + 1];
    float4 a = zs1[v];
    int k = beg;
    for (; k + 3 < end; k += 4) {
        int s0 = csr[k], s1 = csr[k + 1], s2 = csr[k + 2], s3 = csr[k + 3];
        float4 u0 = zs1[s0], u1 = zs1[s1], u2 = zs1[s2], u3 = zs1[s3];
        a.x += (u0.x + u1.x) + (u2.x + u3.x);
        a.y += (u0.y + u1.y) + (u2.y + u3.y);
        a.z += (u0.z + u1.z) + (u2.z + u3.z);
        a.w += (u0.w + u1.w) + (u2.w + u3.w);
    }
    for (; k < end; k++) {
        float4 u = zs1[csr[k]];
        a.x += u.x; a.y += u.y; a.z += u.z; a.w += u.w;
    }
    float d = dis[v];
    a.x *= d; a.y *= d; a.z *= d; a.w *= d;
    float acc[32];
#pragma unroll
    for (int j = 0; j < 32; j++) acc[j] = 0.f;
    for (int kk = 0; kk < 64; kk++) {
        float tv = fmaxf(a.x * sW1[kk] + a.y * sW1[64 + kk] + a.z * sW1[128 + kk]
                         + a.w * sW1[192 + kk] + sb1[kk], 0.f);
#pragma unroll
        for (int j = 0; j < 32; j++) acc[j] += tv * sW2[kk * 32 + j];
    }
    uint4 pk[4];
#pragma unroll
    for (int q = 0; q < 4; q++) {
        pk[q].x = f2bf(acc[8 * q + 0] * d) | (f2bf(acc[8 * q + 1] * d) << 16);
        pk[q].y = f2bf(acc[8 * q + 2] * d) | (f2bf(acc[8 * q + 3] * d) << 16);
        pk[q].z = f2bf(acc[8 * q + 4] * d) | (f2bf(acc[8 * q + 5] * d) << 16);
        pk[q].w = f2bf(acc[8 * q + 6] * d) | (f2bf(acc[8 * q + 7] * d) << 16);
    }
#pragma unroll
    for (int q = 0; q < 4; q++) zs2h[(size_t)v * 4 + q] = pk[q];
}

// prop layer 2: 16 lanes/node, bf16x2/lane, lo|hi source phases, x4 unroll
__global__ __launch_bounds__(256) void k_prop2(const unsigned* __restrict__ zs2h,
        const int* __restrict__ csr, const int* __restrict__ ptr,
        const int* __restrict__ cntLo, const float* __restrict__ dis,
        const float* __restrict__ b2, float* __restrict__ gsum, int n) {
    __shared__ float gacc[32];
    if (threadIdx.x < 32) gacc[threadIdx.x] = 0.f;
    __syncthreads();
    int j = threadIdx.x & 15;
    int v = blockIdx.x * 16 + (threadIdx.x >> 4);
    if (v < n) {
        int beg = ptr[v], end = ptr[v + 1];
        int mid = beg + cntLo[v];
        unsigned su = zs2h[(size_t)v * 16 + j];
        float a0 = __uint_as_float(su << 16);
        float a1 = __uint_as_float(su & 0xffff0000u);
        int k = beg;
#pragma unroll 1
        for (int phase = 0; phase < 2; phase++) {
            int stop = phase ? end : mid;
            for (; k + 3 < stop; k += 4) {
                int s0 = csr[k], s1 = csr[k + 1], s2 = csr[k + 2], s3 = csr[k + 3];
                unsigned u0 = zs2h[(size_t)s0 * 16 + j];
                unsigned u1 = zs2h[(size_t)s1 * 16 + j];
                unsigned u2 = zs2h[(size_t)s2 * 16 + j];
                unsigned u3 = zs2h[(size_t)s3 * 16 + j];
                a0 += (__uint_as_float(u0 << 16) + __uint_as_float(u1 << 16))
                    + (__uint_as_float(u2 << 16) + __uint_as_float(u3 << 16));
                a1 += (__uint_as_float(u0 & 0xffff0000u) + __uint_as_float(u1 & 0xffff0000u))
                    + (__uint_as_float(u2 & 0xffff0000u) + __uint_as_float(u3 & 0xffff0000u));
            }
            for (; k < stop; k++) {
                unsigned u = zs2h[(size_t)csr[k] * 16 + j];
                a0 += __uint_as_float(u << 16);
                a1 += __uint_as_float(u & 0xffff0000u);
            }
        }
        float d = dis[v];
        a0 = fmaxf(a0 * d + b2[2 * j], 0.f);
        a1 = fmaxf(a1 * d + b2[2 * j + 1], 0.f);
        atomicAdd(&gacc[2 * j], a0);
        atomicAdd(&gacc[2 * j + 1], a1);
    }
    __syncthreads();
    if (threadIdx.x < 32) atomicAdd(&gsum[threadIdx.x], gacc[threadIdx.x]);
}

__global__ void k_final(const float* __restrict__ gsum, const float* __restrict__ Wfc,
                        const float* __restrict__ bfc, float* __restrict__ out, int n) {
    __shared__ float s[32];
    int t = threadIdx.x;
    if (t < 32) s[t] = (gsum[t] / (float)n) * Wfc[t];
    __syncthreads();
    if (t == 0) {
        float a = 0.f;
        for (int i = 0; i < 32; i++) a += s[i];
        a += bfc[0];
        out[0] = 1.f / (1.f + expf(-a));
    }
}

// ---------------- launch ----------------

extern "C" void kernel_launch(void* const* d_in, const int* in_sizes, int n_in,
                              void* d_out, int out_size, void* d_ws, size_t ws_size,
                              hipStream_t stream) {
    const float* x    = (const float*)d_in[0];
    const int*   ei   = (const int*)d_in[1];     // int32 per harness contract
    const float* W1   = (const float*)d_in[2];
    const float* b1   = (const float*)d_in[3];
    const float* W2   = (const float*)d_in[4];
    const float* b2   = (const float*)d_in[5];
    const float* Wfc  = (const float*)d_in[6];
    const float* bfc  = (const float*)d_in[7];
    float* out = (float*)d_out;

    const int N = in_sizes[0] / 4;
    const int E = in_sizes[1] / 2;
    const int E4 = E / 4;                              // E divisible by 4 here
    const int nbuck = (N + BWIDTH - 1) >> BSHIFT;      // 782
    const int total = nbuck * PBLK;                    // 200192
    const int nch   = (total + 1023) / 1024;           // 196 (<=1024)
    const int mid   = N / 2;

    auto align = [](size_t v) { return (v + 255) & ~(size_t)255; };
    char* w = (char*)d_ws;
    // region A: hh+part during build; zs1 afterwards (hh dead after k_place)
    size_t hhBytes = align((size_t)total * 4) + align(1024 * 4);
    size_t regA    = hhBytes > (size_t)N * 16 ? hhBytes : (size_t)N * 16;
    char* A = w;               w += align(regA);
    int*   hh   = (int*)A;
    int*   part = (int*)(A + align((size_t)total * 4));
    float* zs1  = (float*)A;
    int*   ptr   = (int*)w;    w += align(((size_t)N + 1) * 4);
    int*   cntLo = (int*)w;    w += align((size_t)N * 4);
    float* dis   = (float*)w;  w += align((size_t)N * 4);
    int*   csr   = (int*)w;    w += align((size_t)E * 4);
    // staging (E*4) aliases zs2h (N*64): staging dead before zs2h written
    char* S = w;               w += align((size_t)E * 4);
    unsigned* staging = (unsigned*)S;
    unsigned* zs2h    = (unsigned*)S;
    float* gsum  = (float*)w;  w += align(32 * 4);

    const int nb = (N + 255) / 256;

    k_histb<<<PBLK, PTHR, 0, stream>>>((const v4i*)(ei + E), E4, nbuck, hh);
    k_scanA<<<nch, 1024, 0, stream>>>(hh, total, part);
    k_scanB<<<1, 1024, 0, stream>>>(part, nch, gsum, ptr, N, E);
    k_scanC<<<nch, 1024, 0, stream>>>(hh, total, part);
    k_place<<<PBLK, PTHR, 0, stream>>>((const v4i*)ei, (const v4i*)(ei + E),
                                       hh, staging, E4, nbuck);
    k_build<<<nbuck, 256, 0, stream>>>(staging, hh, ptr, cntLo, dis, csr, N, E, nbuck, mid);
    k_zs1<<<nb, 256, 0, stream>>>((const float4*)x, dis, (float4*)zs1, N);
    k_prop1mlp<<<nb, 256, 0, stream>>>((const float4*)zs1, csr, ptr, dis, W1, b1, W2,
                                       (uint4*)zs2h, N);
    k_prop2<<<(N + 15) / 16, 256, 0, stream>>>(zs2h, csr, ptr, cntLo, dis, b2, gsum, N);
    k_final<<<1, 64, 0, stream>>>(gsum, Wfc, bfc, out, N);
}

// Round 7
// 185.783 us; speedup vs baseline: 5.6812x; 1.3316x over previous
//
#include <hip/hip_runtime.h>

#define BSHIFT 7
#define BWIDTH 128
#define PBLK   256        // chunks for hist/place (also their grid size)
#define PTHR   1024
#define ECAP   6144       // LDS edge cache in k_build (24KB); avg bucket ~4100

typedef int v4i __attribute__((ext_vector_type(4)));
typedef float v2f __attribute__((ext_vector_type(2)));

// ---------------- fp8 e4m3 helpers (HW cvt with manual fallback) ----------------

#if __has_builtin(__builtin_amdgcn_cvt_pk_f32_fp8) && __has_builtin(__builtin_amdgcn_cvt_pk_fp8_f32)
#define FP8_HW 1
#else
#define FP8_HW 0
#endif

__device__ __forceinline__ unsigned enc1_sw(float f) {
    unsigned u = __float_as_uint(f), s = u >> 31;
    float m = fabsf(f);
    unsigned code;
    if (!(m == m)) code = 0x7F;
    else if (m >= 448.f) code = 0x7E;
    else if (m < 0.015625f) {                 // subnormal: step 2^-9
        code = (unsigned)(int)rintf(m * 512.f);
    } else {
        int e = (int)((__float_as_uint(m) >> 23) & 255) - 127;
        if (e > 8) e = 8;
        float sc = __uint_as_float((unsigned)(130 - e) << 23);   // 2^(3-e)
        int qi = (int)rintf(m * sc);          // in [8,16]
        if (qi >= 16) { e++; qi = 8; }
        code = (e > 8) ? 0x7E : (((unsigned)(e + 7) << 3) | (unsigned)(qi - 8));
    }
    return code | (s << 7);
}

__device__ __forceinline__ float dec1_sw(unsigned b) {
    unsigned s = b >> 7, e = (b >> 3) & 15, m = b & 7;
    float v;
    if (e == 0) v = (float)m * 0.001953125f;                       // m * 2^-9
    else        v = (float)(8 + m) * __uint_as_float((e + 117) << 23); // (8+m)*2^(e-10)
    return s ? -v : v;
}

__device__ __forceinline__ unsigned enc4(float f0, float f1, float f2, float f3) {
#if FP8_HW
    int w = __builtin_amdgcn_cvt_pk_fp8_f32(f0, f1, 0, false);
    w = __builtin_amdgcn_cvt_pk_fp8_f32(f2, f3, w, true);
    return (unsigned)w;
#else
    return enc1_sw(f0) | (enc1_sw(f1) << 8) | (enc1_sw(f2) << 16) | (enc1_sw(f3) << 24);
#endif
}

__device__ __forceinline__ void dec4(unsigned w, float* o) {
#if FP8_HW
    v2f lo = __builtin_amdgcn_cvt_pk_f32_fp8((int)w, false);
    v2f hi = __builtin_amdgcn_cvt_pk_f32_fp8((int)w, true);
    o[0] = lo[0]; o[1] = lo[1]; o[2] = hi[0]; o[3] = hi[1];
#else
    o[0] = dec1_sw(w & 255); o[1] = dec1_sw((w >> 8) & 255);
    o[2] = dec1_sw((w >> 16) & 255); o[3] = dec1_sw(w >> 24);
#endif
}

// ---------------- CSR build (global-atomic-free) ----------------

__global__ __launch_bounds__(PTHR) void k_histb(const v4i* __restrict__ col4,
        int E4, int nbuck, int* __restrict__ hh) {
    __shared__ int h[1024];
    int t = threadIdx.x;
    for (int i = t; i < nbuck; i += PTHR) h[i] = 0;
    __syncthreads();
    int per = (E4 + PBLK - 1) / PBLK;
    int beg = blockIdx.x * per;
    int end = min(beg + per, E4);
    for (int i = beg + t; i < end; i += PTHR) {
        v4i c = __builtin_nontemporal_load(&col4[i]);
        atomicAdd(&h[c[0] >> BSHIFT], 1);
        atomicAdd(&h[c[1] >> BSHIFT], 1);
        atomicAdd(&h[c[2] >> BSHIFT], 1);
        atomicAdd(&h[c[3] >> BSHIFT], 1);
    }
    __syncthreads();
    for (int b = t; b < nbuck; b += PTHR)
        hh[b * PBLK + blockIdx.x] = h[b];
}

__global__ __launch_bounds__(1024) void k_scanA(int* __restrict__ hh, int total,
                                                int* __restrict__ part) {
    __shared__ int s[1024];
    int t = threadIdx.x;
    int i = blockIdx.x * 1024 + t;
    int v = (i < total) ? hh[i] : 0;
    s[t] = v;
    __syncthreads();
    for (int off = 1; off < 1024; off <<= 1) {
        int u = (t >= off) ? s[t - off] : 0;
        __syncthreads();
        s[t] += u;
        __syncthreads();
    }
    if (i < total) hh[i] = s[t] - v;
    if (t == 1023) part[blockIdx.x] = s[t];
}

__global__ __launch_bounds__(1024) void k_scanB(int* __restrict__ part, int nch,
        float* __restrict__ gsum, int* __restrict__ ptr, int N, int E) {
    __shared__ int s[1024];
    int t = threadIdx.x;
    int v = (t < nch) ? part[t] : 0;
    s[t] = v;
    __syncthreads();
    for (int off = 1; off < 1024; off <<= 1) {
        int u = (t >= off) ? s[t - off] : 0;
        __syncthreads();
        s[t] += u;
        __syncthreads();
    }
    if (t < nch) part[t] = s[t] - v;
    if (t < 32) gsum[t] = 0.f;
    if (t == 0) ptr[N] = E;
}

__global__ __launch_bounds__(1024) void k_scanC(int* __restrict__ hh, int total,
                                                const int* __restrict__ part) {
    int i = blockIdx.x * 1024 + threadIdx.x;
    if (i < total) hh[i] += part[blockIdx.x];
}

__global__ __launch_bounds__(PTHR) void k_place(const v4i* __restrict__ row4,
        const v4i* __restrict__ col4, const int* __restrict__ hh,
        unsigned* __restrict__ staging, int E4, int nbuck) {
    __shared__ int sbase[1024];
    __shared__ int lfill[1024];
    int t = threadIdx.x;
    for (int b = t; b < nbuck; b += PTHR) {
        sbase[b] = hh[b * PBLK + blockIdx.x];
        lfill[b] = 0;
    }
    __syncthreads();
    int per = (E4 + PBLK - 1) / PBLK;
    int beg = blockIdx.x * per;
    int end = min(beg + per, E4);
    for (int i = beg + t; i < end; i += PTHR) {
        v4i c = __builtin_nontemporal_load(&col4[i]);
        v4i r = __builtin_nontemporal_load(&row4[i]);
#pragma unroll
        for (int q = 0; q < 4; q++) {
            int b = c[q] >> BSHIFT;
            int pos = sbase[b] + atomicAdd(&lfill[b], 1);
            staging[pos] = (unsigned)r[q] | ((unsigned)(c[q] & (BWIDTH - 1)) << 17);
        }
    }
}

// per-bucket: node degrees -> ptr/dis, CSR slices; bucket edges cached in LDS
__global__ __launch_bounds__(256) void k_build(const unsigned* __restrict__ staging,
        const int* __restrict__ hh, int* __restrict__ ptr,
        float* __restrict__ dis, int* __restrict__ csr, int N, int E, int nbuck) {
    __shared__ unsigned ecache[ECAP];
    __shared__ int hist[BWIDTH], scn[BWIDTH], fl[BWIDTH];
    int b = blockIdx.x;
    int base = hh[b * PBLK];
    int nxt  = (b + 1 < nbuck) ? hh[(b + 1) * PBLK] : E;
    int cnt = nxt - base;
    int t = threadIdx.x;
    bool useC = (cnt <= ECAP);
    if (t < BWIDTH) { hist[t] = 0; fl[t] = 0; }
    __syncthreads();
    if (useC) {
        for (int i = t; i < cnt; i += 256) {
            unsigned p = staging[base + i];
            ecache[i] = p;
            atomicAdd(&hist[p >> 17], 1);
        }
    } else {
        for (int i = t; i < cnt; i += 256)
            atomicAdd(&hist[staging[base + i] >> 17], 1);
    }
    __syncthreads();
    if (t < BWIDTH) scn[t] = hist[t];
    __syncthreads();
    for (int off = 1; off < BWIDTH; off <<= 1) {
        int u = (t < BWIDTH && t >= off) ? scn[t - off] : 0;
        __syncthreads();
        if (t < BWIDTH) scn[t] += u;
        __syncthreads();
    }
    if (t < BWIDTH) {
        int ex = scn[t] - hist[t];
        scn[t] = ex;
        int node = (b << BSHIFT) + t;
        if (node < N) {
            ptr[node] = base + ex;
            dis[node] = rsqrtf((float)(hist[t] + 1));   // +1 self-loop
        }
    }
    __syncthreads();
    for (int i = t; i < cnt; i += 256) {
        unsigned p = useC ? ecache[i] : staging[base + i];
        int c = p >> 17;
        int pos = base + scn[c] + atomicAdd(&fl[c], 1);
        csr[pos] = (int)(p & 0x1FFFFu);
    }
}

// ---------------- GNN compute ----------------

__global__ void k_zs1(const float4* __restrict__ x, const float* __restrict__ dis,
                      float4* __restrict__ zs1, int n) {
    int i = blockIdx.x * blockDim.x + threadIdx.x;
    if (i < n) {
        float d = dis[i];
        float4 v = x[i];
        v.x *= d; v.y *= d; v.z *= d; v.w *= d;
        zs1[i] = v;
    }
}

// fused: p1 = dis*(zs1+gather); t = relu(p1@W1+b1); zs2f8 = fp8((t@W2)*dis)
__global__ __launch_bounds__(256) void k_prop1mlp(const float4* __restrict__ zs1,
        const int* __restrict__ csr, const int* __restrict__ ptr,
        const float* __restrict__ dis, const float* __restrict__ W1,
        const float* __restrict__ b1, const float* __restrict__ W2,
        uint4* __restrict__ zs2f8, int n) {
    __shared__ float sW1[256];
    __shared__ float sb1[64];
    __shared__ float sW2[2048];
    for (int i = threadIdx.x; i < 256; i += 256) sW1[i] = W1[i];
    if (threadIdx.x < 64) sb1[threadIdx.x] = b1[threadIdx.x];
    for (int i = threadIdx.x; i < 2048; i += 256) sW2[i] = W2[i];
    __syncthreads();
    int v = blockIdx.x * 256 + threadIdx.x;
    if (v >= n) return;
    int beg = ptr[v], end = ptr[v + 1];
    float4 a = zs1[v];
    int k = beg;
    for (; k + 3 < end; k += 4) {
        int s0 = csr[k], s1 = csr[k + 1], s2 = csr[k + 2], s3 = csr[k + 3];
        float4 u0 = zs1[s0], u1 = zs1[s1], u2 = zs1[s2], u3 = zs1[s3];
        a.x += (u0.x + u1.x) + (u2.x + u3.x);
        a.y += (u0.y + u1.y) + (u2.y + u3.y);
        a.z += (u0.z + u1.z) + (u2.z + u3.z);
        a.w += (u0.w + u1.w) + (u2.w + u3.w);
    }
    for (; k < end; k++) {
        float4 u = zs1[csr[k]];
        a.x += u.x; a.y += u.y; a.z += u.z; a.w += u.w;
    }
    float d = dis[v];
    a.x *= d; a.y *= d; a.z *= d; a.w *= d;
    float acc[32];
#pragma unroll
    for (int j = 0; j < 32; j++) acc[j] = 0.f;
    for (int kk = 0; kk < 64; kk++) {
        float tv = fmaxf(a.x * sW1[kk] + a.y * sW1[64 + kk] + a.z * sW1[128 + kk]
                         + a.w * sW1[192 + kk] + sb1[kk], 0.f);
#pragma unroll
        for (int j = 0; j < 32; j++) acc[j] += tv * sW2[kk * 32 + j];
    }
    uint4 w0, w1;
    w0.x = enc4(acc[0] * d,  acc[1] * d,  acc[2] * d,  acc[3] * d);
    w0.y = enc4(acc[4] * d,  acc[5] * d,  acc[6] * d,  acc[7] * d);
    w0.z = enc4(acc[8] * d,  acc[9] * d,  acc[10] * d, acc[11] * d);
    w0.w = enc4(acc[12] * d, acc[13] * d, acc[14] * d, acc[15] * d);
    w1.x = enc4(acc[16] * d, acc[17] * d, acc[18] * d, acc[19] * d);
    w1.y = enc4(acc[20] * d, acc[21] * d, acc[22] * d, acc[23] * d);
    w1.z = enc4(acc[24] * d, acc[25] * d, acc[26] * d, acc[27] * d);
    w1.w = enc4(acc[28] * d, acc[29] * d, acc[30] * d, acc[31] * d);
    zs2f8[(size_t)v * 2]     = w0;
    zs2f8[(size_t)v * 2 + 1] = w1;
}

// prop layer 2: 8 lanes/node, 4 fp8 features per lane (32B/node, 3.2MB L2-resident)
__global__ __launch_bounds__(256) void k_prop2(const unsigned* __restrict__ zs2f8,
        const int* __restrict__ csr, const int* __restrict__ ptr,
        const float* __restrict__ dis, const float* __restrict__ b2,
        float* __restrict__ gsum, int n) {
    __shared__ float gacc[32];
    if (threadIdx.x < 32) gacc[threadIdx.x] = 0.f;
    __syncthreads();
    int j = threadIdx.x & 7;
    int v = (blockIdx.x * blockDim.x + threadIdx.x) >> 3;
    if (v < n) {
        int beg = ptr[v], end = ptr[v + 1];
        float a[4];
        dec4(zs2f8[(size_t)v * 8 + j], a);      // self term (already *dis)
        int k = beg;
        for (; k + 3 < end; k += 4) {
            int s0 = csr[k], s1 = csr[k + 1], s2 = csr[k + 2], s3 = csr[k + 3];
            unsigned w0 = zs2f8[(size_t)s0 * 8 + j];
            unsigned w1 = zs2f8[(size_t)s1 * 8 + j];
            unsigned w2 = zs2f8[(size_t)s2 * 8 + j];
            unsigned w3 = zs2f8[(size_t)s3 * 8 + j];
            float t0[4], t1[4], t2[4], t3[4];
            dec4(w0, t0); dec4(w1, t1); dec4(w2, t2); dec4(w3, t3);
#pragma unroll
            for (int m = 0; m < 4; m++)
                a[m] += (t0[m] + t1[m]) + (t2[m] + t3[m]);
        }
        for (; k < end; k++) {
            float t0[4];
            dec4(zs2f8[(size_t)csr[k] * 8 + j], t0);
#pragma unroll
            for (int m = 0; m < 4; m++) a[m] += t0[m];
        }
        float d = dis[v];
        int f = j * 4;
#pragma unroll
        for (int m = 0; m < 4; m++) {
            float r = fmaxf(a[m] * d + b2[f + m], 0.f);
            atomicAdd(&gacc[f + m], r);
        }
    }
    __syncthreads();
    if (threadIdx.x < 32) atomicAdd(&gsum[threadIdx.x], gacc[threadIdx.x]);
}

__global__ void k_final(const float* __restrict__ gsum, const float* __restrict__ Wfc,
                        const float* __restrict__ bfc, float* __restrict__ out, int n) {
    __shared__ float s[32];
    int t = threadIdx.x;
    if (t < 32) s[t] = (gsum[t] / (float)n) * Wfc[t];
    __syncthreads();
    if (t == 0) {
        float a = 0.f;
        for (int i = 0; i < 32; i++) a += s[i];
        a += bfc[0];
        out[0] = 1.f / (1.f + expf(-a));
    }
}

// ---------------- launch ----------------

extern "C" void kernel_launch(void* const* d_in, const int* in_sizes, int n_in,
                              void* d_out, int out_size, void* d_ws, size_t ws_size,
                              hipStream_t stream) {
    const float* x    = (const float*)d_in[0];
    const int*   ei   = (const int*)d_in[1];     // int32 per harness contract
    const float* W1   = (const float*)d_in[2];
    const float* b1   = (const float*)d_in[3];
    const float* W2   = (const float*)d_in[4];
    const float* b2   = (const float*)d_in[5];
    const float* Wfc  = (const float*)d_in[6];
    const float* bfc  = (const float*)d_in[7];
    float* out = (float*)d_out;

    const int N = in_sizes[0] / 4;
    const int E = in_sizes[1] / 2;
    const int E4 = E / 4;
    const int nbuck = (N + BWIDTH - 1) >> BSHIFT;      // 782
    const int total = nbuck * PBLK;                    // 200192
    const int nch   = (total + 1023) / 1024;           // 196 (<=1024)

    auto align = [](size_t v) { return (v + 255) & ~(size_t)255; };
    char* w = (char*)d_ws;
    // region A: hh+part during build; zs1 afterwards (hh dead after k_build)
    size_t hhBytes = align((size_t)total * 4) + align(1024 * 4);
    size_t regA    = hhBytes > (size_t)N * 16 ? hhBytes : (size_t)N * 16;
    char* A = w;               w += align(regA);
    int*   hh   = (int*)A;
    int*   part = (int*)(A + align((size_t)total * 4));
    float* zs1  = (float*)A;
    int*   ptr   = (int*)w;    w += align(((size_t)N + 1) * 4);
    float* dis   = (float*)w;  w += align((size_t)N * 4);
    int*   csr   = (int*)w;    w += align((size_t)E * 4);
    // staging (E*4) aliases zs2f8 (N*32B): staging dead before zs2f8 written
    char* S = w;               w += align((size_t)E * 4);
    unsigned* staging = (unsigned*)S;
    unsigned* zs2f8   = (unsigned*)S;
    float* gsum  = (float*)w;  w += align(32 * 4);

    const int nb = (N + 255) / 256;

    k_histb<<<PBLK, PTHR, 0, stream>>>((const v4i*)(ei + E), E4, nbuck, hh);
    k_scanA<<<nch, 1024, 0, stream>>>(hh, total, part);
    k_scanB<<<1, 1024, 0, stream>>>(part, nch, gsum, ptr, N, E);
    k_scanC<<<nch, 1024, 0, stream>>>(hh, total, part);
    k_place<<<PBLK, PTHR, 0, stream>>>((const v4i*)ei, (const v4i*)(ei + E),
                                       hh, staging, E4, nbuck);
    k_build<<<nbuck, 256, 0, stream>>>(staging, hh, ptr, dis, csr, N, E, nbuck);
    k_zs1<<<nb, 256, 0, stream>>>((const float4*)x, dis, (float4*)zs1, N);
    k_prop1mlp<<<nb, 256, 0, stream>>>((const float4*)zs1, csr, ptr, dis, W1, b1, W2,
                                       (uint4*)zs2f8, N);
    k_prop2<<<(N * 8 + 255) / 256, 256, 0, stream>>>(zs2f8, csr, ptr, dis, b2, gsum, N);
    k_final<<<1, 64, 0, stream>>>(gsum, Wfc, bfc, out, N);
}